// Round 10
// baseline (475.462 us; speedup 1.0000x reference)
//
#include <hip/hip_runtime.h>

#define B_ 8
#define P_ 8192
#define M_ 2048
#define K_ 32
#define CIN_ 64
#define C3_ 128
#define BM_ (B_*M_)
#define NTOT_f 524288.0f
#define BN_EPS_ 1e-5f
#define POOLCAP 128
#define XW_STR 112   // ushort stride of x/h rows in LDS (224 B, uniform b128 spread)
#define W3_STR 72    // ushort stride of W3 rows in LDS (144 B; 64 would be 8-way conflict)

typedef __attribute__((ext_vector_type(8))) short bf16x8;
typedef __attribute__((ext_vector_type(4))) float f32x4;

// workspace layout (in floats): idx | featsT | y3max | y3min | stats | SoA xyz
#define WS_FT    (BM_*K_)
#define WS_Y3MAX (WS_FT + B_*P_*CIN_)
#define WS_Y3MIN (WS_Y3MAX + BM_*C3_)
#define WS_STATS (WS_Y3MIN + BM_*C3_)        // 512 floats
#define WS_XS    (WS_STATS + 512)
#define WS_YS    (WS_XS + B_*P_)
#define WS_ZS    (WS_YS + B_*P_)

__device__ inline int center_index(int m) {
  const double step = (double)(P_ - 1) / (double)(M_ - 1);
  return (m == M_ - 1) ? (P_ - 1) : (int)((double)m * step);
}

__device__ inline unsigned short f2bf(float f) {
  unsigned int u = __float_as_uint(f);
  unsigned int r = (u + 0x7fffu + ((u >> 16) & 1u)) >> 16;
  return (unsigned short)r;
}

// strict (non-contracted) f32 sum of squares: (x2+y2)+z2  [golden assoc, R6]
__device__ inline float sq3(float a, float b, float c) {
  return __fadd_rn(__fadd_rn(__fmul_rn(a, a), __fmul_rn(b, b)), __fmul_rn(c, c));
}

// ---------------- prep: xyz AoS -> SoA (coalesced KNN loads) ---------------
__global__ __launch_bounds__(256) void k_prep(const float* __restrict__ xyz,
                                              float* __restrict__ Xs,
                                              float* __restrict__ Ys,
                                              float* __restrict__ Zs) {
  int gid = blockIdx.x * 256 + threadIdx.x;   // over B_*P_
  float x = xyz[gid * 3 + 0];
  float y = xyz[gid * 3 + 1];
  float z = xyz[gid * 3 + 2];
  Xs[gid] = x; Ys[gid] = y; Zs[gid] = z;
}

// ---------------- transpose feats (B,C,P) -> featsT (B,P,C) ----------------
__global__ __launch_bounds__(256) void k_transpose(const float* __restrict__ feats,
                                                   float* __restrict__ ftT) {
  __shared__ float tile[64][65];
  int b = blockIdx.x >> 7;
  int p0 = (blockIdx.x & 127) << 6;
  const float* fb = feats + (size_t)b * CIN_ * P_;
  float* ob = ftT + (size_t)b * P_ * CIN_;
  for (int i = threadIdx.x; i < 64 * 64; i += 256) {
    int c = i >> 6, pp = i & 63;
    tile[c][pp] = fb[c * P_ + p0 + pp];
  }
  __syncthreads();
  for (int i = threadIdx.x; i < 64 * 64; i += 256) {
    int pp = i >> 6, c = i & 63;
    ob[(size_t)(p0 + pp) * CIN_ + c] = tile[c][pp];
  }
}

// ---------------- KNN: streaming pool + bitonic compact, golden-f32 d2 -----
__device__ inline void cmpx_elem(float& v, int& ix, int i, int size, int d) {
  float pv = __shfl_xor(v, d);
  int pi = __shfl_xor(ix, d);
  bool up = ((i & size) == 0);
  bool lower = ((i & d) == 0);
  bool less = (v < pv) || (v == pv && ix < pi);
  bool keep = (lower == up) ? less : !less;
  if (!keep) { v = pv; ix = pi; }
}

__device__ void pool_compact(float* pv_, int* pi_, int& pc, float& kth, int lane) {
  __threadfence_block();
  float v0 = (lane < pc) ? pv_[lane] : __builtin_inff();
  int   i0 = (lane < pc) ? pi_[lane] : 0x7fffffff;
  float v1 = (lane + 64 < pc) ? pv_[lane + 64] : __builtin_inff();
  int   i1 = (lane + 64 < pc) ? pi_[lane + 64] : 0x7fffffff;
  for (int size = 2; size <= 128; size <<= 1) {
    if (size == 128) {
      bool less = (v0 < v1) || (v0 == v1 && i0 < i1);
      if (!less) { float tv = v0; v0 = v1; v1 = tv; int ti = i0; i0 = i1; i1 = ti; }
    }
    for (int d = (size == 128 ? 32 : (size >> 1)); d >= 1; d >>= 1) {
      cmpx_elem(v0, i0, lane, size, d);
      cmpx_elem(v1, i1, lane + 64, size, d);
    }
  }
  if (lane < 32) { pv_[lane] = v0; pi_[lane] = i0; }
  __threadfence_block();
  pc = 32;
  kth = __shfl(v0, 31);
}

__global__ __launch_bounds__(256) void k_knn(const float* __restrict__ xyz,
                                             const float* __restrict__ Xs,
                                             const float* __restrict__ Ys,
                                             const float* __restrict__ Zs,
                                             float* __restrict__ centers_out,
                                             int* __restrict__ knn_idx) {
  __shared__ float pvals[4][4][POOLCAP];
  __shared__ int   pidxs[4][4][POOLCAP];
  const int w = threadIdx.x >> 6, lane = threadIdx.x & 63;
  const int gw = blockIdx.x * 4 + w;
  const int cid0 = gw * 4;
  const int b = cid0 >> 11;
  const float* xyzb = xyz + (size_t)b * P_ * 3;
  const float* Xb = Xs + (size_t)b * P_;
  const float* Yb = Ys + (size_t)b * P_;
  const float* Zb = Zs + (size_t)b * P_;

  float cx[4], cy[4], cz[4], ccs[4], kth[4];
  int pc[4];
  #pragma unroll
  for (int cc = 0; cc < 4; cc++) {
    int m = (cid0 + cc) & (M_ - 1);
    int ci = center_index(m);
    cx[cc] = xyzb[ci * 3 + 0];
    cy[cc] = xyzb[ci * 3 + 1];
    cz[cc] = xyzb[ci * 3 + 2];
    ccs[cc] = sq3(cx[cc], cy[cc], cz[cc]);
    kth[cc] = __builtin_inff();
    pc[cc] = 0;
  }
  if (lane < 12) {
    int cc = lane / 3, c = lane % 3;
    int m = (cid0 + cc) & (M_ - 1);
    int ci = center_index(m);
    centers_out[(size_t)(cid0 + cc) * 3 + c] = xyzb[ci * 3 + c];
  }

  for (int bi = 0; bi < P_ / 64; bi++) {
    int p = bi * 64 + lane;
    float px = Xb[p], py = Yb[p], pz = Zb[p];
    float pp = sq3(px, py, pz);
    #pragma unroll
    for (int cc = 0; cc < 4; cc++) {
      float dot = __fmul_rn(cx[cc], px);
      dot = __builtin_fmaf(cy[cc], py, dot);
      dot = __builtin_fmaf(cz[cc], pz, dot);
      float d2 = __fsub_rn(__fadd_rn(ccs[cc], pp), __fmul_rn(2.0f, dot));
      bool pass = d2 < kth[cc];
      unsigned long long mask = __ballot(pass);
      if (mask) {
        int cnt = __popcll(mask);
        if (pc[cc] + cnt > POOLCAP)
          pool_compact(&pvals[w][cc][0], &pidxs[w][cc][0], pc[cc], kth[cc], lane);
        int rank = __popcll(mask & ((1ull << lane) - 1ull));
        if (pass) {
          pvals[w][cc][pc[cc] + rank] = d2;
          pidxs[w][cc][pc[cc] + rank] = p;
        }
        pc[cc] += cnt;
      }
    }
  }
  #pragma unroll
  for (int cc = 0; cc < 4; cc++) {
    pool_compact(&pvals[w][cc][0], &pidxs[w][cc][0], pc[cc], kth[cc], lane);
    if (lane < K_) knn_idx[(size_t)(cid0 + cc) * K_ + lane] = pidxs[w][cc][lane];
  }
}

// ---------------- MFMA helpers ----------------
// Channel permutation: x cols [0..63]=feats, [64..66]=local_xyz, [67..95]=0.
__device__ inline void gather_mfma(const float* __restrict__ xyz,
                                   const float* __restrict__ ftT,
                                   const int* __restrict__ knn,
                                   int cid, int lane,
                                   unsigned short* __restrict__ xq) {
  const int b = cid >> 11;
  const int m = cid & (M_ - 1);
  const int ci = center_index(m);
  const float* xyzb = xyz + (size_t)b * P_ * 3;
  const int r = lane >> 1, hf = lane & 1;
  const int p = knn[(size_t)cid * K_ + r];
  const float* frow = ftT + ((size_t)b * P_ + p) * CIN_ + hf * 32;
  unsigned short* row = xq + r * XW_STR;
  #pragma unroll
  for (int i = 0; i < 8; i++) {
    float4 v = *(const float4*)(frow + i * 4);
    ushort4 u = make_ushort4(f2bf(v.x), f2bf(v.y), f2bf(v.z), f2bf(v.w));
    *(ushort4*)(row + hf * 32 + i * 4) = u;
  }
  if (hf == 0) {
    float dx = xyzb[p * 3 + 0] - xyzb[ci * 3 + 0];
    float dy = xyzb[p * 3 + 1] - xyzb[ci * 3 + 1];
    float dz = xyzb[p * 3 + 2] - xyzb[ci * 3 + 2];
    ushort4 u = make_ushort4(f2bf(dx), f2bf(dy), f2bf(dz), 0);
    *(ushort4*)(row + 64) = u;
  } else {
    ushort4 z = make_ushort4(0, 0, 0, 0);
    #pragma unroll
    for (int i = 0; i < 7; i++) *(ushort4*)(row + 68 + i * 4) = z;
  }
}

__device__ inline void load_w1_frags(const float* __restrict__ W1, int lane, bf16x8 (&w1f)[4][3]) {
  const int o16 = lane & 15, q = lane >> 4;
  #pragma unroll
  for (int nt = 0; nt < 4; nt++) {
    const float* wr = W1 + (nt * 16 + o16) * 67;
    #pragma unroll
    for (int s = 0; s < 3; s++) {
      bf16x8 f;
      #pragma unroll
      for (int j = 0; j < 8; j++) {
        int c = s * 32 + q * 8 + j;
        float v = (c < 64) ? wr[c + 3] : ((c < 67) ? wr[c - 64] : 0.0f);
        f[j] = (short)f2bf(v);
      }
      w1f[nt][s] = f;
    }
  }
}

__device__ inline void load_w2_frags(const float* __restrict__ W2, int lane, bf16x8 (&w2f)[4][2]) {
  const int o16 = lane & 15, q = lane >> 4;
  #pragma unroll
  for (int nt = 0; nt < 4; nt++) {
    const float* wr = W2 + (nt * 16 + o16) * 64;
    #pragma unroll
    for (int s = 0; s < 2; s++) {
      bf16x8 f;
      #pragma unroll
      for (int j = 0; j < 8; j++) f[j] = (short)f2bf(wr[s * 32 + q * 8 + j]);
      w2f[nt][s] = f;
    }
  }
}

__device__ inline bf16x8 lds_afrag(const unsigned short* __restrict__ xq, int mt, int s, int lane) {
  return *(const bf16x8*)(xq + (mt * 16 + (lane & 15)) * XW_STR + s * 32 + (lane >> 4) * 8);
}

// ---------------- pass 1: G1 -> stats(y1) ----------------
__global__ __launch_bounds__(256, 3) void k_mf1(const float* __restrict__ xyz,
                                                const float* __restrict__ ftT,
                                                const int* __restrict__ knn,
                                                const float* __restrict__ W1,
                                                const float* __restrict__ b1,
                                                float* __restrict__ stats) {
  __shared__ __align__(16) unsigned short xw[4][32 * XW_STR];
  __shared__ float sld[128];
  const int t = threadIdx.x, w = t >> 6, lane = t & 63, o16 = lane & 15;
  if (t < 128) sld[t] = 0.0f;

  bf16x8 w1f[4][3];
  load_w1_frags(W1, lane, w1f);
  float b1l[4], sacc[4], qacc[4];
  #pragma unroll
  for (int nt = 0; nt < 4; nt++) { b1l[nt] = b1[nt * 16 + o16]; sacc[nt] = 0.f; qacc[nt] = 0.f; }
  __syncthreads();

  unsigned short* xq = &xw[w][0];
  const int cid0 = blockIdx.x * 32 + w * 8;
  for (int n = 0; n < 8; n++) {
    gather_mfma(xyz, ftT, knn, cid0 + n, lane, xq);
    f32x4 acc[2][4];
    #pragma unroll
    for (int mt = 0; mt < 2; mt++)
      #pragma unroll
      for (int nt = 0; nt < 4; nt++) acc[mt][nt] = (f32x4){0.f, 0.f, 0.f, 0.f};
    #pragma unroll
    for (int s = 0; s < 3; s++) {
      bf16x8 a0 = lds_afrag(xq, 0, s, lane);
      bf16x8 a1 = lds_afrag(xq, 1, s, lane);
      #pragma unroll
      for (int nt = 0; nt < 4; nt++) {
        acc[0][nt] = __builtin_amdgcn_mfma_f32_16x16x32_bf16(a0, w1f[nt][s], acc[0][nt], 0, 0, 0);
        acc[1][nt] = __builtin_amdgcn_mfma_f32_16x16x32_bf16(a1, w1f[nt][s], acc[1][nt], 0, 0, 0);
      }
    }
    #pragma unroll
    for (int nt = 0; nt < 4; nt++)
      #pragma unroll
      for (int mt = 0; mt < 2; mt++)
        #pragma unroll
        for (int rr = 0; rr < 4; rr++) {
          float y = acc[mt][nt][rr] + b1l[nt];
          sacc[nt] += y;
          qacc[nt] = fmaf(y, y, qacc[nt]);
        }
  }
  #pragma unroll
  for (int nt = 0; nt < 4; nt++) {
    float s = sacc[nt]; s += __shfl_xor(s, 16); s += __shfl_xor(s, 32);
    float qq = qacc[nt]; qq += __shfl_xor(qq, 16); qq += __shfl_xor(qq, 32);
    if (lane < 16) { atomicAdd(&sld[nt * 16 + lane], s); atomicAdd(&sld[64 + nt * 16 + lane], qq); }
  }
  __syncthreads();
  if (t < 64) { atomicAdd(&stats[t], sld[t]); atomicAdd(&stats[64 + t], sld[64 + t]); }
}

// ---------------- pass 2: G1 -> bn1 -> G2 -> stats(y2) ----------------
__global__ __launch_bounds__(256, 2) void k_mf2(const float* __restrict__ xyz,
                                                const float* __restrict__ ftT,
                                                const int* __restrict__ knn,
                                                const float* __restrict__ W1,
                                                const float* __restrict__ b1,
                                                const float* __restrict__ g1,
                                                const float* __restrict__ be1,
                                                const float* __restrict__ W2,
                                                const float* __restrict__ b2,
                                                float* __restrict__ stats) {
  __shared__ __align__(16) unsigned short xw[4][32 * XW_STR];
  __shared__ float sld[128];
  const int t = threadIdx.x, w = t >> 6, lane = t & 63, o16 = lane & 15, q = lane >> 4;
  if (t < 128) sld[t] = 0.0f;

  bf16x8 w1f[4][3];
  bf16x8 w2f[4][2];
  load_w1_frags(W1, lane, w1f);
  load_w2_frags(W2, lane, w2f);
  float b1l[4], sc1l[4], sh1l[4], b2l[4], sacc[4], qacc[4];
  #pragma unroll
  for (int nt = 0; nt < 4; nt++) {
    int o = nt * 16 + o16;
    float mean = stats[o] * (1.0f / NTOT_f);
    float var = stats[64 + o] * (1.0f / NTOT_f) - mean * mean;
    float rs = rsqrtf(var + BN_EPS_);
    sc1l[nt] = g1[o] * rs;
    sh1l[nt] = be1[o] - mean * sc1l[nt];
    b1l[nt] = b1[o];
    b2l[nt] = b2[o];
    sacc[nt] = 0.f; qacc[nt] = 0.f;
  }
  __syncthreads();

  unsigned short* xq = &xw[w][0];
  const int cid0 = blockIdx.x * 32 + w * 8;
  for (int n = 0; n < 8; n++) {
    gather_mfma(xyz, ftT, knn, cid0 + n, lane, xq);
    f32x4 acc[2][4];
    #pragma unroll
    for (int mt = 0; mt < 2; mt++)
      #pragma unroll
      for (int nt = 0; nt < 4; nt++) acc[mt][nt] = (f32x4){0.f, 0.f, 0.f, 0.f};
    #pragma unroll
    for (int s = 0; s < 3; s++) {
      bf16x8 a0 = lds_afrag(xq, 0, s, lane);
      bf16x8 a1 = lds_afrag(xq, 1, s, lane);
      #pragma unroll
      for (int nt = 0; nt < 4; nt++) {
        acc[0][nt] = __builtin_amdgcn_mfma_f32_16x16x32_bf16(a0, w1f[nt][s], acc[0][nt], 0, 0, 0);
        acc[1][nt] = __builtin_amdgcn_mfma_f32_16x16x32_bf16(a1, w1f[nt][s], acc[1][nt], 0, 0, 0);
      }
    }
    #pragma unroll
    for (int nt = 0; nt < 4; nt++)
      #pragma unroll
      for (int mt = 0; mt < 2; mt++)
        #pragma unroll
        for (int rr = 0; rr < 4; rr++) {
          float y = acc[mt][nt][rr] + b1l[nt];
          float h = fmaxf(fmaf(y, sc1l[nt], sh1l[nt]), 0.0f);
          xq[(mt * 16 + q * 4 + rr) * XW_STR + nt * 16 + o16] = f2bf(h);
        }
    f32x4 acc2[2][4];
    #pragma unroll
    for (int mt = 0; mt < 2; mt++)
      #pragma unroll
      for (int nt = 0; nt < 4; nt++) acc2[mt][nt] = (f32x4){0.f, 0.f, 0.f, 0.f};
    #pragma unroll
    for (int s = 0; s < 2; s++) {
      bf16x8 a0 = lds_afrag(xq, 0, s, lane);
      bf16x8 a1 = lds_afrag(xq, 1, s, lane);
      #pragma unroll
      for (int nt = 0; nt < 4; nt++) {
        acc2[0][nt] = __builtin_amdgcn_mfma_f32_16x16x32_bf16(a0, w2f[nt][s], acc2[0][nt], 0, 0, 0);
        acc2[1][nt] = __builtin_amdgcn_mfma_f32_16x16x32_bf16(a1, w2f[nt][s], acc2[1][nt], 0, 0, 0);
      }
    }
    #pragma unroll
    for (int nt = 0; nt < 4; nt++)
      #pragma unroll
      for (int mt = 0; mt < 2; mt++)
        #pragma unroll
        for (int rr = 0; rr < 4; rr++) {
          float y = acc2[mt][nt][rr] + b2l[nt];
          sacc[nt] += y;
          qacc[nt] = fmaf(y, y, qacc[nt]);
        }
  }
  #pragma unroll
  for (int nt = 0; nt < 4; nt++) {
    float s = sacc[nt]; s += __shfl_xor(s, 16); s += __shfl_xor(s, 32);
    float qq = qacc[nt]; qq += __shfl_xor(qq, 16); qq += __shfl_xor(qq, 32);
    if (lane < 16) { atomicAdd(&sld[nt * 16 + lane], s); atomicAdd(&sld[64 + nt * 16 + lane], qq); }
  }
  __syncthreads();
  if (t < 64) { atomicAdd(&stats[128 + t], sld[t]); atomicAdd(&stats[192 + t], sld[64 + t]); }
}

// ---------------- pass 3: G1->bn1->G2->bn2->G3 -> stats(y3) + max/min ------
__global__ __launch_bounds__(256, 2) void k_mf3(const float* __restrict__ xyz,
                                                const float* __restrict__ ftT,
                                                const int* __restrict__ knn,
                                                const float* __restrict__ W1,
                                                const float* __restrict__ b1,
                                                const float* __restrict__ g1,
                                                const float* __restrict__ be1,
                                                const float* __restrict__ W2,
                                                const float* __restrict__ b2,
                                                const float* __restrict__ g2,
                                                const float* __restrict__ be2,
                                                const float* __restrict__ W3,
                                                const float* __restrict__ b3,
                                                float* __restrict__ stats,
                                                float* __restrict__ y3max,
                                                float* __restrict__ y3min) {
  __shared__ __align__(16) unsigned short xw[4][32 * XW_STR];
  __shared__ __align__(16) unsigned short ws3[128 * W3_STR];
  __shared__ float sld[256];
  const int t = threadIdx.x, w = t >> 6, lane = t & 63, o16 = lane & 15, q = lane >> 4;
  if (t < 256) sld[t] = 0.0f;
  for (int i = t; i < 128 * 64; i += 256) {
    int o = i >> 6, c = i & 63;
    ws3[o * W3_STR + c] = f2bf(W3[i]);
  }

  bf16x8 w1f[4][3];
  bf16x8 w2f[4][2];
  load_w1_frags(W1, lane, w1f);
  load_w2_frags(W2, lane, w2f);
  float b1l[4], sc1l[4], sh1l[4], b2l[4], sc2l[4], sh2l[4];
  #pragma unroll
  for (int nt = 0; nt < 4; nt++) {
    int o = nt * 16 + o16;
    float mean = stats[o] * (1.0f / NTOT_f);
    float var = stats[64 + o] * (1.0f / NTOT_f) - mean * mean;
    float rs = rsqrtf(var + BN_EPS_);
    sc1l[nt] = g1[o] * rs;
    sh1l[nt] = be1[o] - mean * sc1l[nt];
    b1l[nt] = b1[o];
    float mean2 = stats[128 + o] * (1.0f / NTOT_f);
    float var2 = stats[192 + o] * (1.0f / NTOT_f) - mean2 * mean2;
    float rs2 = rsqrtf(var2 + BN_EPS_);
    sc2l[nt] = g2[o] * rs2;
    sh2l[nt] = be2[o] - mean2 * sc2l[nt];
    b2l[nt] = b2[o];
  }
  float b3l[8], sacc[8], qacc[8];
  #pragma unroll
  for (int nt = 0; nt < 8; nt++) { b3l[nt] = b3[nt * 16 + o16]; sacc[nt] = 0.f; qacc[nt] = 0.f; }
  __syncthreads();

  unsigned short* xq = &xw[w][0];
  const int cid0 = blockIdx.x * 32 + w * 8;
  for (int n = 0; n < 8; n++) {
    const int cid = cid0 + n;
    gather_mfma(xyz, ftT, knn, cid, lane, xq);
    f32x4 acc[2][4];
    #pragma unroll
    for (int mt = 0; mt < 2; mt++)
      #pragma unroll
      for (int nt = 0; nt < 4; nt++) acc[mt][nt] = (f32x4){0.f, 0.f, 0.f, 0.f};
    #pragma unroll
    for (int s = 0; s < 3; s++) {
      bf16x8 a0 = lds_afrag(xq, 0, s, lane);
      bf16x8 a1 = lds_afrag(xq, 1, s, lane);
      #pragma unroll
      for (int nt = 0; nt < 4; nt++) {
        acc[0][nt] = __builtin_amdgcn_mfma_f32_16x16x32_bf16(a0, w1f[nt][s], acc[0][nt], 0, 0, 0);
        acc[1][nt] = __builtin_amdgcn_mfma_f32_16x16x32_bf16(a1, w1f[nt][s], acc[1][nt], 0, 0, 0);
      }
    }
    #pragma unroll
    for (int nt = 0; nt < 4; nt++)
      #pragma unroll
      for (int mt = 0; mt < 2; mt++)
        #pragma unroll
        for (int rr = 0; rr < 4; rr++) {
          float y = acc[mt][nt][rr] + b1l[nt];
          float h = fmaxf(fmaf(y, sc1l[nt], sh1l[nt]), 0.0f);
          xq[(mt * 16 + q * 4 + rr) * XW_STR + nt * 16 + o16] = f2bf(h);
        }
    #pragma unroll
    for (int mt = 0; mt < 2; mt++)
      #pragma unroll
      for (int nt = 0; nt < 4; nt++) acc[mt][nt] = (f32x4){0.f, 0.f, 0.f, 0.f};
    #pragma unroll
    for (int s = 0; s < 2; s++) {
      bf16x8 a0 = lds_afrag(xq, 0, s, lane);
      bf16x8 a1 = lds_afrag(xq, 1, s, lane);
      #pragma unroll
      for (int nt = 0; nt < 4; nt++) {
        acc[0][nt] = __builtin_amdgcn_mfma_f32_16x16x32_bf16(a0, w2f[nt][s], acc[0][nt], 0, 0, 0);
        acc[1][nt] = __builtin_amdgcn_mfma_f32_16x16x32_bf16(a1, w2f[nt][s], acc[1][nt], 0, 0, 0);
      }
    }
    #pragma unroll
    for (int nt = 0; nt < 4; nt++)
      #pragma unroll
      for (int mt = 0; mt < 2; mt++)
        #pragma unroll
        for (int rr = 0; rr < 4; rr++) {
          float y = acc[mt][nt][rr] + b2l[nt];
          float h = fmaxf(fmaf(y, sc2l[nt], sh2l[nt]), 0.0f);
          xq[(mt * 16 + q * 4 + rr) * XW_STR + nt * 16 + o16] = f2bf(h);
        }
    f32x4 acc3[2][8];
    #pragma unroll
    for (int mt = 0; mt < 2; mt++)
      #pragma unroll
      for (int nt = 0; nt < 8; nt++) acc3[mt][nt] = (f32x4){0.f, 0.f, 0.f, 0.f};
    #pragma unroll
    for (int s = 0; s < 2; s++) {
      bf16x8 a0 = lds_afrag(xq, 0, s, lane);
      bf16x8 a1 = lds_afrag(xq, 1, s, lane);
      #pragma unroll
      for (int nt = 0; nt < 8; nt++) {
        bf16x8 bf = *(const bf16x8*)(ws3 + (nt * 16 + o16) * W3_STR + s * 32 + q * 8);
        acc3[0][nt] = __builtin_amdgcn_mfma_f32_16x16x32_bf16(a0, bf, acc3[0][nt], 0, 0, 0);
        acc3[1][nt] = __builtin_amdgcn_mfma_f32_16x16x32_bf16(a1, bf, acc3[1][nt], 0, 0, 0);
      }
    }
    #pragma unroll
    for (int nt = 0; nt < 8; nt++) {
      float mx = -__builtin_inff(), mn = __builtin_inff();
      #pragma unroll
      for (int mt = 0; mt < 2; mt++)
        #pragma unroll
        for (int rr = 0; rr < 4; rr++) {
          float y = acc3[mt][nt][rr] + b3l[nt];
          sacc[nt] += y;
          qacc[nt] = fmaf(y, y, qacc[nt]);
          mx = fmaxf(mx, y);
          mn = fminf(mn, y);
        }
      mx = fmaxf(mx, __shfl_xor(mx, 16)); mx = fmaxf(mx, __shfl_xor(mx, 32));
      mn = fminf(mn, __shfl_xor(mn, 16)); mn = fminf(mn, __shfl_xor(mn, 32));
      if (lane < 16) {
        y3max[(size_t)cid * C3_ + nt * 16 + lane] = mx;
        y3min[(size_t)cid * C3_ + nt * 16 + lane] = mn;
      }
    }
  }
  #pragma unroll
  for (int nt = 0; nt < 8; nt++) {
    float s = sacc[nt]; s += __shfl_xor(s, 16); s += __shfl_xor(s, 32);
    float qq = qacc[nt]; qq += __shfl_xor(qq, 16); qq += __shfl_xor(qq, 32);
    if (lane < 16) { atomicAdd(&sld[nt * 16 + lane], s); atomicAdd(&sld[128 + nt * 16 + lane], qq); }
  }
  __syncthreads();
  if (t < 128) { atomicAdd(&stats[256 + t], sld[t]); atomicAdd(&stats[384 + t], sld[128 + t]); }
}

// ---------------- final output ----------------
__global__ __launch_bounds__(256) void k_out(const float* __restrict__ y3max,
                                             const float* __restrict__ y3min,
                                             const float* __restrict__ stats,
                                             const float* __restrict__ g3,
                                             const float* __restrict__ be3,
                                             float* __restrict__ outp) {
  __shared__ float sc[128], sh[128];
  const int t = threadIdx.x;
  if (t < 128) {
    float mean = stats[256 + t] * (1.0f / NTOT_f);
    float var = stats[384 + t] * (1.0f / NTOT_f) - mean * mean;
    float rs = rsqrtf(var + BN_EPS_);
    float s = g3[t] * rs;
    sc[t] = s;
    sh[t] = be3[t] - mean * s;
  }
  __syncthreads();
  int gid = blockIdx.x * 256 + t;
  int m = gid & (M_ - 1);
  int o = (gid >> 11) & 127;
  int b = gid >> 18;
  float s = sc[o], h = sh[o];
  size_t src = ((size_t)(b * M_ + m)) * C3_ + o;
  float v = (s >= 0.0f) ? y3max[src] : y3min[src];
  outp[gid] = fmaxf(fmaf(v, s, h), 0.0f);
}

extern "C" void kernel_launch(void* const* d_in, const int* in_sizes, int n_in,
                              void* d_out, int out_size, void* d_ws, size_t ws_size,
                              hipStream_t stream) {
  const float* xyz  = (const float*)d_in[0];
  const float* feats = (const float*)d_in[1];
  const float* W1 = (const float*)d_in[2];
  const float* b1 = (const float*)d_in[3];
  const float* g1 = (const float*)d_in[4];
  const float* be1 = (const float*)d_in[5];
  const float* W2 = (const float*)d_in[6];
  const float* b2 = (const float*)d_in[7];
  const float* g2 = (const float*)d_in[8];
  const float* be2 = (const float*)d_in[9];
  const float* W3 = (const float*)d_in[10];
  const float* b3 = (const float*)d_in[11];
  const float* g3 = (const float*)d_in[12];
  const float* be3 = (const float*)d_in[13];

  float* out = (float*)d_out;
  float* centers = out;                  // B*M*3
  float* outp = out + (size_t)B_ * M_ * 3;

  float* wsf = (float*)d_ws;
  int* idx = (int*)wsf;
  float* ftT = wsf + WS_FT;
  float* y3max = wsf + WS_Y3MAX;
  float* y3min = wsf + WS_Y3MIN;
  float* stats = wsf + WS_STATS;
  float* Xs = wsf + WS_XS;
  float* Ys = wsf + WS_YS;
  float* Zs = wsf + WS_ZS;

  hipMemsetAsync(stats, 0, 512 * sizeof(float), stream);
  k_prep<<<(B_ * P_) / 256, 256, 0, stream>>>(xyz, Xs, Ys, Zs);
  k_transpose<<<1024, 256, 0, stream>>>(feats, ftT);
  k_knn<<<1024, 256, 0, stream>>>(xyz, Xs, Ys, Zs, centers, idx);
  k_mf1<<<512, 256, 0, stream>>>(xyz, ftT, idx, W1, b1, stats);
  k_mf2<<<512, 256, 0, stream>>>(xyz, ftT, idx, W1, b1, g1, be1, W2, b2, stats);
  k_mf3<<<512, 256, 0, stream>>>(xyz, ftT, idx, W1, b1, g1, be1, W2, b2, g2, be2,
                                 W3, b3, stats, y3max, y3min);
  k_out<<<8192, 256, 0, stream>>>(y3max, y3min, stats, g3, be3, outp);
}

// Round 11
// 402.396 us; speedup vs baseline: 1.1816x; 1.1816x over previous
//
#include <hip/hip_runtime.h>

#define B_ 8
#define P_ 8192
#define M_ 2048
#define K_ 32
#define CIN_ 64
#define C3_ 128
#define BM_ (B_*P_/4)
#define NTOT_f 524288.0f
#define BN_EPS_ 1e-5f
#define POOLCAP 128
#define XW_STR 112   // ushort stride of x/h rows in LDS (224 B, uniform b128 spread)
#define W3_STR 72    // ushort stride of W3 rows in LDS (144 B; 64 would be 8-way conflict)

typedef __attribute__((ext_vector_type(8))) short bf16x8;
typedef __attribute__((ext_vector_type(4))) float f32x4;

// workspace layout (in floats): idx | featsT | y3max | y3min | stats | y2(bf16)
#define WS_FT    (BM_*K_)
#define WS_Y3MAX (WS_FT + B_*P_*CIN_)
#define WS_Y3MIN (WS_Y3MAX + BM_*C3_)
#define WS_STATS (WS_Y3MIN + BM_*C3_)        // 512 floats
#define WS_Y2F   (WS_STATS + 512)            // ushort[BM_*K_*CIN_] from here

__device__ inline int center_index(int m) {
  const double step = (double)(P_ - 1) / (double)(M_ - 1);
  return (m == M_ - 1) ? (P_ - 1) : (int)((double)m * step);
}

__device__ inline unsigned short f2bf(float f) {
  unsigned int u = __float_as_uint(f);
  unsigned int r = (u + 0x7fffu + ((u >> 16) & 1u)) >> 16;
  return (unsigned short)r;
}
__device__ inline float bf2f(unsigned short s) {
  return __uint_as_float(((unsigned int)s) << 16);
}

// strict (non-contracted) f32 sum of squares: (x2+y2)+z2  [golden assoc, R6]
__device__ inline float sq3(float a, float b, float c) {
  return __fadd_rn(__fadd_rn(__fmul_rn(a, a), __fmul_rn(b, b)), __fmul_rn(c, c));
}

// ---------------- transpose feats (B,C,P) -> featsT (B,P,C) ----------------
__global__ __launch_bounds__(256) void k_transpose(const float* __restrict__ feats,
                                                   float* __restrict__ ftT) {
  __shared__ float tile[64][65];
  int b = blockIdx.x >> 7;
  int p0 = (blockIdx.x & 127) << 6;
  const float* fb = feats + (size_t)b * CIN_ * P_;
  float* ob = ftT + (size_t)b * P_ * CIN_;
  for (int i = threadIdx.x; i < 64 * 64; i += 256) {
    int c = i >> 6, pp = i & 63;
    tile[c][pp] = fb[c * P_ + p0 + pp];
  }
  __syncthreads();
  for (int i = threadIdx.x; i < 64 * 64; i += 256) {
    int pp = i >> 6, c = i & 63;
    ob[(size_t)(p0 + pp) * CIN_ + c] = tile[c][pp];
  }
}

// ---------------- KNN: streaming pool + bitonic compact (R9 proven, AoS) ---
__device__ inline void cmpx_elem(float& v, int& ix, int i, int size, int d) {
  float pv = __shfl_xor(v, d);
  int pi = __shfl_xor(ix, d);
  bool up = ((i & size) == 0);
  bool lower = ((i & d) == 0);
  bool less = (v < pv) || (v == pv && ix < pi);
  bool keep = (lower == up) ? less : !less;
  if (!keep) { v = pv; ix = pi; }
}

__device__ void pool_compact(float* pv_, int* pi_, int& pc, float& kth, int lane) {
  __threadfence_block();
  float v0 = (lane < pc) ? pv_[lane] : __builtin_inff();
  int   i0 = (lane < pc) ? pi_[lane] : 0x7fffffff;
  float v1 = (lane + 64 < pc) ? pv_[lane + 64] : __builtin_inff();
  int   i1 = (lane + 64 < pc) ? pi_[lane + 64] : 0x7fffffff;
  for (int size = 2; size <= 128; size <<= 1) {
    if (size == 128) {
      bool less = (v0 < v1) || (v0 == v1 && i0 < i1);
      if (!less) { float tv = v0; v0 = v1; v1 = tv; int ti = i0; i0 = i1; i1 = ti; }
    }
    for (int d = (size == 128 ? 32 : (size >> 1)); d >= 1; d >>= 1) {
      cmpx_elem(v0, i0, lane, size, d);
      cmpx_elem(v1, i1, lane + 64, size, d);
    }
  }
  if (lane < 32) { pv_[lane] = v0; pi_[lane] = i0; }
  __threadfence_block();
  pc = 32;
  kth = __shfl(v0, 31);
}

__global__ __launch_bounds__(256) void k_knn(const float* __restrict__ xyz,
                                             float* __restrict__ centers_out,
                                             int* __restrict__ knn_idx) {
  __shared__ float pvals[4][4][POOLCAP];
  __shared__ int   pidxs[4][4][POOLCAP];
  const int w = threadIdx.x >> 6, lane = threadIdx.x & 63;
  const int gw = blockIdx.x * 4 + w;
  const int cid0 = gw * 4;
  const int b = cid0 >> 11;
  const float* xyzb = xyz + (size_t)b * P_ * 3;

  float cx[4], cy[4], cz[4], ccs[4], kth[4];
  int pc[4];
  #pragma unroll
  for (int cc = 0; cc < 4; cc++) {
    int m = (cid0 + cc) & (M_ - 1);
    int ci = center_index(m);
    cx[cc] = xyzb[ci * 3 + 0];
    cy[cc] = xyzb[ci * 3 + 1];
    cz[cc] = xyzb[ci * 3 + 2];
    ccs[cc] = sq3(cx[cc], cy[cc], cz[cc]);
    kth[cc] = __builtin_inff();
    pc[cc] = 0;
  }
  if (lane < 12) {
    int cc = lane / 3, c = lane % 3;
    int m = (cid0 + cc) & (M_ - 1);
    int ci = center_index(m);
    centers_out[(size_t)(cid0 + cc) * 3 + c] = xyzb[ci * 3 + c];
  }

  for (int bi = 0; bi < P_ / 64; bi++) {
    int p = bi * 64 + lane;
    float px = xyzb[p * 3 + 0], py = xyzb[p * 3 + 1], pz = xyzb[p * 3 + 2];
    float pp = sq3(px, py, pz);
    #pragma unroll
    for (int cc = 0; cc < 4; cc++) {
      float dot = __fmul_rn(cx[cc], px);
      dot = __builtin_fmaf(cy[cc], py, dot);
      dot = __builtin_fmaf(cz[cc], pz, dot);
      float d2 = __fsub_rn(__fadd_rn(ccs[cc], pp), __fmul_rn(2.0f, dot));
      bool pass = d2 < kth[cc];
      unsigned long long mask = __ballot(pass);
      if (mask) {
        int cnt = __popcll(mask);
        if (pc[cc] + cnt > POOLCAP)
          pool_compact(&pvals[w][cc][0], &pidxs[w][cc][0], pc[cc], kth[cc], lane);
        int rank = __popcll(mask & ((1ull << lane) - 1ull));
        if (pass) {
          pvals[w][cc][pc[cc] + rank] = d2;
          pidxs[w][cc][pc[cc] + rank] = p;
        }
        pc[cc] += cnt;
      }
    }
  }
  #pragma unroll
  for (int cc = 0; cc < 4; cc++) {
    pool_compact(&pvals[w][cc][0], &pidxs[w][cc][0], pc[cc], kth[cc], lane);
    if (lane < K_) knn_idx[(size_t)(cid0 + cc) * K_ + lane] = pidxs[w][cc][lane];
  }
}

// ---------------- MFMA helpers ----------------
__device__ inline void gather_mfma(const float* __restrict__ xyz,
                                   const float* __restrict__ ftT,
                                   const int* __restrict__ knn,
                                   int cid, int lane,
                                   unsigned short* __restrict__ xq) {
  const int b = cid >> 11;
  const int m = cid & (M_ - 1);
  const int ci = center_index(m);
  const float* xyzb = xyz + (size_t)b * P_ * 3;
  const int r = lane >> 1, hf = lane & 1;
  const int p = knn[(size_t)cid * K_ + r];
  const float* frow = ftT + ((size_t)b * P_ + p) * CIN_ + hf * 32;
  unsigned short* row = xq + r * XW_STR;
  #pragma unroll
  for (int i = 0; i < 8; i++) {
    float4 v = *(const float4*)(frow + i * 4);
    ushort4 u = make_ushort4(f2bf(v.x), f2bf(v.y), f2bf(v.z), f2bf(v.w));
    *(ushort4*)(row + hf * 32 + i * 4) = u;
  }
  if (hf == 0) {
    float dx = xyzb[p * 3 + 0] - xyzb[ci * 3 + 0];
    float dy = xyzb[p * 3 + 1] - xyzb[ci * 3 + 1];
    float dz = xyzb[p * 3 + 2] - xyzb[ci * 3 + 2];
    ushort4 u = make_ushort4(f2bf(dx), f2bf(dy), f2bf(dz), 0);
    *(ushort4*)(row + 64) = u;
  } else {
    ushort4 z = make_ushort4(0, 0, 0, 0);
    #pragma unroll
    for (int i = 0; i < 7; i++) *(ushort4*)(row + 68 + i * 4) = z;
  }
}

__device__ inline void load_w1_frags(const float* __restrict__ W1, int lane, bf16x8 (&w1f)[4][3]) {
  const int o16 = lane & 15, q = lane >> 4;
  #pragma unroll
  for (int nt = 0; nt < 4; nt++) {
    const float* wr = W1 + (nt * 16 + o16) * 67;
    #pragma unroll
    for (int s = 0; s < 3; s++) {
      bf16x8 f;
      #pragma unroll
      for (int j = 0; j < 8; j++) {
        int c = s * 32 + q * 8 + j;
        float v = (c < 64) ? wr[c + 3] : ((c < 67) ? wr[c - 64] : 0.0f);
        f[j] = (short)f2bf(v);
      }
      w1f[nt][s] = f;
    }
  }
}

__device__ inline void load_w2_frags(const float* __restrict__ W2, int lane, bf16x8 (&w2f)[4][2]) {
  const int o16 = lane & 15, q = lane >> 4;
  #pragma unroll
  for (int nt = 0; nt < 4; nt++) {
    const float* wr = W2 + (nt * 16 + o16) * 64;
    #pragma unroll
    for (int s = 0; s < 2; s++) {
      bf16x8 f;
      #pragma unroll
      for (int j = 0; j < 8; j++) f[j] = (short)f2bf(wr[s * 32 + q * 8 + j]);
      w2f[nt][s] = f;
    }
  }
}

__device__ inline bf16x8 lds_afrag(const unsigned short* __restrict__ xq, int mt, int s, int lane) {
  return *(const bf16x8*)(xq + (mt * 16 + (lane & 15)) * XW_STR + s * 32 + (lane >> 4) * 8);
}

// ---------------- pass 1: G1 -> stats(y1) ----------------
__global__ __launch_bounds__(256, 3) void k_mf1(const float* __restrict__ xyz,
                                                const float* __restrict__ ftT,
                                                const int* __restrict__ knn,
                                                const float* __restrict__ W1,
                                                const float* __restrict__ b1,
                                                float* __restrict__ stats) {
  __shared__ __align__(16) unsigned short xw[4][32 * XW_STR];
  __shared__ float sld[128];
  const int t = threadIdx.x, w = t >> 6, lane = t & 63, o16 = lane & 15;
  if (t < 128) sld[t] = 0.0f;

  bf16x8 w1f[4][3];
  load_w1_frags(W1, lane, w1f);
  float b1l[4], sacc[4], qacc[4];
  #pragma unroll
  for (int nt = 0; nt < 4; nt++) { b1l[nt] = b1[nt * 16 + o16]; sacc[nt] = 0.f; qacc[nt] = 0.f; }
  __syncthreads();

  unsigned short* xq = &xw[w][0];
  const int cid0 = blockIdx.x * 32 + w * 8;
  for (int n = 0; n < 8; n++) {
    gather_mfma(xyz, ftT, knn, cid0 + n, lane, xq);
    f32x4 acc[2][4];
    #pragma unroll
    for (int mt = 0; mt < 2; mt++)
      #pragma unroll
      for (int nt = 0; nt < 4; nt++) acc[mt][nt] = (f32x4){0.f, 0.f, 0.f, 0.f};
    #pragma unroll
    for (int s = 0; s < 3; s++) {
      bf16x8 a0 = lds_afrag(xq, 0, s, lane);
      bf16x8 a1 = lds_afrag(xq, 1, s, lane);
      #pragma unroll
      for (int nt = 0; nt < 4; nt++) {
        acc[0][nt] = __builtin_amdgcn_mfma_f32_16x16x32_bf16(a0, w1f[nt][s], acc[0][nt], 0, 0, 0);
        acc[1][nt] = __builtin_amdgcn_mfma_f32_16x16x32_bf16(a1, w1f[nt][s], acc[1][nt], 0, 0, 0);
      }
    }
    #pragma unroll
    for (int nt = 0; nt < 4; nt++)
      #pragma unroll
      for (int mt = 0; mt < 2; mt++)
        #pragma unroll
        for (int rr = 0; rr < 4; rr++) {
          float y = acc[mt][nt][rr] + b1l[nt];
          sacc[nt] += y;
          qacc[nt] = fmaf(y, y, qacc[nt]);
        }
  }
  #pragma unroll
  for (int nt = 0; nt < 4; nt++) {
    float s = sacc[nt]; s += __shfl_xor(s, 16); s += __shfl_xor(s, 32);
    float qq = qacc[nt]; qq += __shfl_xor(qq, 16); qq += __shfl_xor(qq, 32);
    if (lane < 16) { atomicAdd(&sld[nt * 16 + lane], s); atomicAdd(&sld[64 + nt * 16 + lane], qq); }
  }
  __syncthreads();
  if (t < 64) { atomicAdd(&stats[t], sld[t]); atomicAdd(&stats[64 + t], sld[64 + t]); }
}

// ---------------- pass 2: G1 -> bn1 -> G2 -> stats(y2) [+ store y2 bf16] ---
__global__ __launch_bounds__(256, 2) void k_mf2(const float* __restrict__ xyz,
                                                const float* __restrict__ ftT,
                                                const int* __restrict__ knn,
                                                const float* __restrict__ W1,
                                                const float* __restrict__ b1,
                                                const float* __restrict__ g1,
                                                const float* __restrict__ be1,
                                                const float* __restrict__ W2,
                                                const float* __restrict__ b2,
                                                float* __restrict__ stats,
                                                unsigned short* __restrict__ y2b) {
  __shared__ __align__(16) unsigned short xw[4][32 * XW_STR];
  __shared__ float sld[128];
  const int t = threadIdx.x, w = t >> 6, lane = t & 63, o16 = lane & 15, q = lane >> 4;
  if (t < 128) sld[t] = 0.0f;

  bf16x8 w1f[4][3];
  bf16x8 w2f[4][2];
  load_w1_frags(W1, lane, w1f);
  load_w2_frags(W2, lane, w2f);
  float b1l[4], sc1l[4], sh1l[4], b2l[4], sacc[4], qacc[4];
  #pragma unroll
  for (int nt = 0; nt < 4; nt++) {
    int o = nt * 16 + o16;
    float mean = stats[o] * (1.0f / NTOT_f);
    float var = stats[64 + o] * (1.0f / NTOT_f) - mean * mean;
    float rs = rsqrtf(var + BN_EPS_);
    sc1l[nt] = g1[o] * rs;
    sh1l[nt] = be1[o] - mean * sc1l[nt];
    b1l[nt] = b1[o];
    b2l[nt] = b2[o];
    sacc[nt] = 0.f; qacc[nt] = 0.f;
  }
  __syncthreads();

  unsigned short* xq = &xw[w][0];
  const int cid0 = blockIdx.x * 32 + w * 8;
  for (int n = 0; n < 8; n++) {
    gather_mfma(xyz, ftT, knn, cid0 + n, lane, xq);
    f32x4 acc[2][4];
    #pragma unroll
    for (int mt = 0; mt < 2; mt++)
      #pragma unroll
      for (int nt = 0; nt < 4; nt++) acc[mt][nt] = (f32x4){0.f, 0.f, 0.f, 0.f};
    #pragma unroll
    for (int s = 0; s < 3; s++) {
      bf16x8 a0 = lds_afrag(xq, 0, s, lane);
      bf16x8 a1 = lds_afrag(xq, 1, s, lane);
      #pragma unroll
      for (int nt = 0; nt < 4; nt++) {
        acc[0][nt] = __builtin_amdgcn_mfma_f32_16x16x32_bf16(a0, w1f[nt][s], acc[0][nt], 0, 0, 0);
        acc[1][nt] = __builtin_amdgcn_mfma_f32_16x16x32_bf16(a1, w1f[nt][s], acc[1][nt], 0, 0, 0);
      }
    }
    #pragma unroll
    for (int nt = 0; nt < 4; nt++)
      #pragma unroll
      for (int mt = 0; mt < 2; mt++)
        #pragma unroll
        for (int rr = 0; rr < 4; rr++) {
          float y = acc[mt][nt][rr] + b1l[nt];
          float h = fmaxf(fmaf(y, sc1l[nt], sh1l[nt]), 0.0f);
          xq[(mt * 16 + q * 4 + rr) * XW_STR + nt * 16 + o16] = f2bf(h);
        }
    f32x4 acc2[2][4];
    #pragma unroll
    for (int mt = 0; mt < 2; mt++)
      #pragma unroll
      for (int nt = 0; nt < 4; nt++) acc2[mt][nt] = (f32x4){0.f, 0.f, 0.f, 0.f};
    #pragma unroll
    for (int s = 0; s < 2; s++) {
      bf16x8 a0 = lds_afrag(xq, 0, s, lane);
      bf16x8 a1 = lds_afrag(xq, 1, s, lane);
      #pragma unroll
      for (int nt = 0; nt < 4; nt++) {
        acc2[0][nt] = __builtin_amdgcn_mfma_f32_16x16x32_bf16(a0, w2f[nt][s], acc2[0][nt], 0, 0, 0);
        acc2[1][nt] = __builtin_amdgcn_mfma_f32_16x16x32_bf16(a1, w2f[nt][s], acc2[1][nt], 0, 0, 0);
      }
    }
    #pragma unroll
    for (int nt = 0; nt < 4; nt++)
      #pragma unroll
      for (int mt = 0; mt < 2; mt++)
        #pragma unroll
        for (int rr = 0; rr < 4; rr++) {
          float y = acc2[mt][nt][rr] + b2l[nt];
          sacc[nt] += y;
          qacc[nt] = fmaf(y, y, qacc[nt]);
          if (y2b) xq[(mt * 16 + q * 4 + rr) * XW_STR + nt * 16 + o16] = f2bf(y);
        }
    if (y2b) {
      unsigned short* dst = y2b + (size_t)(cid0 + n) * 2048;
      #pragma unroll
      for (int j = 0; j < 8; j++) {
        int chunk = j * 64 + lane;
        int r = chunk >> 4, c = (chunk & 15) * 4;
        *(ushort4*)(dst + chunk * 4) = *(const ushort4*)(xq + r * XW_STR + c);
      }
    }
  }
  #pragma unroll
  for (int nt = 0; nt < 4; nt++) {
    float s = sacc[nt]; s += __shfl_xor(s, 16); s += __shfl_xor(s, 32);
    float qq = qacc[nt]; qq += __shfl_xor(qq, 16); qq += __shfl_xor(qq, 32);
    if (lane < 16) { atomicAdd(&sld[nt * 16 + lane], s); atomicAdd(&sld[64 + nt * 16 + lane], qq); }
  }
  __syncthreads();
  if (t < 64) { atomicAdd(&stats[128 + t], sld[t]); atomicAdd(&stats[192 + t], sld[64 + t]); }
}

// ---------------- pass 3 (fast): y2 -> bn2 -> G3 -> stats(y3) + max/min ----
__global__ __launch_bounds__(256, 2) void k_mf3f(const unsigned short* __restrict__ y2b,
                                                 const float* __restrict__ g2,
                                                 const float* __restrict__ be2,
                                                 const float* __restrict__ W3,
                                                 const float* __restrict__ b3,
                                                 float* __restrict__ stats,
                                                 float* __restrict__ y3max,
                                                 float* __restrict__ y3min) {
  __shared__ __align__(16) unsigned short xw[4][32 * XW_STR];
  __shared__ __align__(16) unsigned short ws3[128 * W3_STR];
  __shared__ float sld[256];
  __shared__ __align__(16) float sc2s[64], sh2s[64];
  const int t = threadIdx.x, w = t >> 6, lane = t & 63, o16 = lane & 15, q = lane >> 4;
  if (t < 256) sld[t] = 0.0f;
  for (int i = t; i < 128 * 64; i += 256) {
    int o = i >> 6, c = i & 63;
    ws3[o * W3_STR + c] = f2bf(W3[i]);
  }
  if (t < 64) {
    float mean2 = stats[128 + t] * (1.0f / NTOT_f);
    float var2 = stats[192 + t] * (1.0f / NTOT_f) - mean2 * mean2;
    float rs2 = rsqrtf(var2 + BN_EPS_);
    float sc = g2[t] * rs2;
    sc2s[t] = sc;
    sh2s[t] = be2[t] - mean2 * sc;
  }
  float b3l[8], sacc[8], qacc[8];
  #pragma unroll
  for (int nt = 0; nt < 8; nt++) { b3l[nt] = b3[nt * 16 + o16]; sacc[nt] = 0.f; qacc[nt] = 0.f; }
  __syncthreads();

  unsigned short* xq = &xw[w][0];
  const int cid0 = blockIdx.x * 32 + w * 8;
  for (int n = 0; n < 8; n++) {
    const int cid = cid0 + n;
    const unsigned short* src = y2b + (size_t)cid * 2048;
    #pragma unroll
    for (int j = 0; j < 8; j++) {
      int chunk = j * 64 + lane;
      int r = chunk >> 4, c = (chunk & 15) * 4;
      ushort4 u = *(const ushort4*)(src + chunk * 4);
      float4 sc4 = *(const float4*)(&sc2s[c]);
      float4 sh4 = *(const float4*)(&sh2s[c]);
      ushort4 h;
      h.x = f2bf(fmaxf(fmaf(bf2f(u.x), sc4.x, sh4.x), 0.0f));
      h.y = f2bf(fmaxf(fmaf(bf2f(u.y), sc4.y, sh4.y), 0.0f));
      h.z = f2bf(fmaxf(fmaf(bf2f(u.z), sc4.z, sh4.z), 0.0f));
      h.w = f2bf(fmaxf(fmaf(bf2f(u.w), sc4.w, sh4.w), 0.0f));
      *(ushort4*)(xq + r * XW_STR + c) = h;
    }
    f32x4 acc3[2][8];
    #pragma unroll
    for (int mt = 0; mt < 2; mt++)
      #pragma unroll
      for (int nt = 0; nt < 8; nt++) acc3[mt][nt] = (f32x4){0.f, 0.f, 0.f, 0.f};
    #pragma unroll
    for (int s = 0; s < 2; s++) {
      bf16x8 a0 = lds_afrag(xq, 0, s, lane);
      bf16x8 a1 = lds_afrag(xq, 1, s, lane);
      #pragma unroll
      for (int nt = 0; nt < 8; nt++) {
        bf16x8 bf = *(const bf16x8*)(ws3 + (nt * 16 + o16) * W3_STR + s * 32 + q * 8);
        acc3[0][nt] = __builtin_amdgcn_mfma_f32_16x16x32_bf16(a0, bf, acc3[0][nt], 0, 0, 0);
        acc3[1][nt] = __builtin_amdgcn_mfma_f32_16x16x32_bf16(a1, bf, acc3[1][nt], 0, 0, 0);
      }
    }
    #pragma unroll
    for (int nt = 0; nt < 8; nt++) {
      float mx = -__builtin_inff(), mn = __builtin_inff();
      #pragma unroll
      for (int mt = 0; mt < 2; mt++)
        #pragma unroll
        for (int rr = 0; rr < 4; rr++) {
          float y = acc3[mt][nt][rr] + b3l[nt];
          sacc[nt] += y;
          qacc[nt] = fmaf(y, y, qacc[nt]);
          mx = fmaxf(mx, y);
          mn = fminf(mn, y);
        }
      mx = fmaxf(mx, __shfl_xor(mx, 16)); mx = fmaxf(mx, __shfl_xor(mx, 32));
      mn = fminf(mn, __shfl_xor(mn, 16)); mn = fminf(mn, __shfl_xor(mn, 32));
      if (lane < 16) {
        y3max[(size_t)cid * C3_ + nt * 16 + lane] = mx;
        y3min[(size_t)cid * C3_ + nt * 16 + lane] = mn;
      }
    }
  }
  #pragma unroll
  for (int nt = 0; nt < 8; nt++) {
    float s = sacc[nt]; s += __shfl_xor(s, 16); s += __shfl_xor(s, 32);
    float qq = qacc[nt]; qq += __shfl_xor(qq, 16); qq += __shfl_xor(qq, 32);
    if (lane < 16) { atomicAdd(&sld[nt * 16 + lane], s); atomicAdd(&sld[128 + nt * 16 + lane], qq); }
  }
  __syncthreads();
  if (t < 128) { atomicAdd(&stats[256 + t], sld[t]); atomicAdd(&stats[384 + t], sld[128 + t]); }
}

// ---------------- pass 3 (full fallback): G1->bn1->G2->bn2->G3 -------------
__global__ __launch_bounds__(256, 2) void k_mf3(const float* __restrict__ xyz,
                                                const float* __restrict__ ftT,
                                                const int* __restrict__ knn,
                                                const float* __restrict__ W1,
                                                const float* __restrict__ b1,
                                                const float* __restrict__ g1,
                                                const float* __restrict__ be1,
                                                const float* __restrict__ W2,
                                                const float* __restrict__ b2,
                                                const float* __restrict__ g2,
                                                const float* __restrict__ be2,
                                                const float* __restrict__ W3,
                                                const float* __restrict__ b3,
                                                float* __restrict__ stats,
                                                float* __restrict__ y3max,
                                                float* __restrict__ y3min) {
  __shared__ __align__(16) unsigned short xw[4][32 * XW_STR];
  __shared__ __align__(16) unsigned short ws3[128 * W3_STR];
  __shared__ float sld[256];
  const int t = threadIdx.x, w = t >> 6, lane = t & 63, o16 = lane & 15, q = lane >> 4;
  if (t < 256) sld[t] = 0.0f;
  for (int i = t; i < 128 * 64; i += 256) {
    int o = i >> 6, c = i & 63;
    ws3[o * W3_STR + c] = f2bf(W3[i]);
  }

  bf16x8 w1f[4][3];
  bf16x8 w2f[4][2];
  load_w1_frags(W1, lane, w1f);
  load_w2_frags(W2, lane, w2f);
  float b1l[4], sc1l[4], sh1l[4], b2l[4], sc2l[4], sh2l[4];
  #pragma unroll
  for (int nt = 0; nt < 4; nt++) {
    int o = nt * 16 + o16;
    float mean = stats[o] * (1.0f / NTOT_f);
    float var = stats[64 + o] * (1.0f / NTOT_f) - mean * mean;
    float rs = rsqrtf(var + BN_EPS_);
    sc1l[nt] = g1[o] * rs;
    sh1l[nt] = be1[o] - mean * sc1l[nt];
    b1l[nt] = b1[o];
    float mean2 = stats[128 + o] * (1.0f / NTOT_f);
    float var2 = stats[192 + o] * (1.0f / NTOT_f) - mean2 * mean2;
    float rs2 = rsqrtf(var2 + BN_EPS_);
    sc2l[nt] = g2[o] * rs2;
    sh2l[nt] = be2[o] - mean2 * sc2l[nt];
    b2l[nt] = b2[o];
  }
  float b3l[8], sacc[8], qacc[8];
  #pragma unroll
  for (int nt = 0; nt < 8; nt++) { b3l[nt] = b3[nt * 16 + o16]; sacc[nt] = 0.f; qacc[nt] = 0.f; }
  __syncthreads();

  unsigned short* xq = &xw[w][0];
  const int cid0 = blockIdx.x * 32 + w * 8;
  for (int n = 0; n < 8; n++) {
    const int cid = cid0 + n;
    gather_mfma(xyz, ftT, knn, cid, lane, xq);
    f32x4 acc[2][4];
    #pragma unroll
    for (int mt = 0; mt < 2; mt++)
      #pragma unroll
      for (int nt = 0; nt < 4; nt++) acc[mt][nt] = (f32x4){0.f, 0.f, 0.f, 0.f};
    #pragma unroll
    for (int s = 0; s < 3; s++) {
      bf16x8 a0 = lds_afrag(xq, 0, s, lane);
      bf16x8 a1 = lds_afrag(xq, 1, s, lane);
      #pragma unroll
      for (int nt = 0; nt < 4; nt++) {
        acc[0][nt] = __builtin_amdgcn_mfma_f32_16x16x32_bf16(a0, w1f[nt][s], acc[0][nt], 0, 0, 0);
        acc[1][nt] = __builtin_amdgcn_mfma_f32_16x16x32_bf16(a1, w1f[nt][s], acc[1][nt], 0, 0, 0);
      }
    }
    #pragma unroll
    for (int nt = 0; nt < 4; nt++)
      #pragma unroll
      for (int mt = 0; mt < 2; mt++)
        #pragma unroll
        for (int rr = 0; rr < 4; rr++) {
          float y = acc[mt][nt][rr] + b1l[nt];
          float h = fmaxf(fmaf(y, sc1l[nt], sh1l[nt]), 0.0f);
          xq[(mt * 16 + q * 4 + rr) * XW_STR + nt * 16 + o16] = f2bf(h);
        }
    #pragma unroll
    for (int mt = 0; mt < 2; mt++)
      #pragma unroll
      for (int nt = 0; nt < 4; nt++) acc[mt][nt] = (f32x4){0.f, 0.f, 0.f, 0.f};
    #pragma unroll
    for (int s = 0; s < 2; s++) {
      bf16x8 a0 = lds_afrag(xq, 0, s, lane);
      bf16x8 a1 = lds_afrag(xq, 1, s, lane);
      #pragma unroll
      for (int nt = 0; nt < 4; nt++) {
        acc[0][nt] = __builtin_amdgcn_mfma_f32_16x16x32_bf16(a0, w2f[nt][s], acc[0][nt], 0, 0, 0);
        acc[1][nt] = __builtin_amdgcn_mfma_f32_16x16x32_bf16(a1, w2f[nt][s], acc[1][nt], 0, 0, 0);
      }
    }
    #pragma unroll
    for (int nt = 0; nt < 4; nt++)
      #pragma unroll
      for (int mt = 0; mt < 2; mt++)
        #pragma unroll
        for (int rr = 0; rr < 4; rr++) {
          float y = acc[mt][nt][rr] + b2l[nt];
          float h = fmaxf(fmaf(y, sc2l[nt], sh2l[nt]), 0.0f);
          xq[(mt * 16 + q * 4 + rr) * XW_STR + nt * 16 + o16] = f2bf(h);
        }
    f32x4 acc3[2][8];
    #pragma unroll
    for (int mt = 0; mt < 2; mt++)
      #pragma unroll
      for (int nt = 0; nt < 8; nt++) acc3[mt][nt] = (f32x4){0.f, 0.f, 0.f, 0.f};
    #pragma unroll
    for (int s = 0; s < 2; s++) {
      bf16x8 a0 = lds_afrag(xq, 0, s, lane);
      bf16x8 a1 = lds_afrag(xq, 1, s, lane);
      #pragma unroll
      for (int nt = 0; nt < 8; nt++) {
        bf16x8 bf = *(const bf16x8*)(ws3 + (nt * 16 + o16) * W3_STR + s * 32 + q * 8);
        acc3[0][nt] = __builtin_amdgcn_mfma_f32_16x16x32_bf16(a0, bf, acc3[0][nt], 0, 0, 0);
        acc3[1][nt] = __builtin_amdgcn_mfma_f32_16x16x32_bf16(a1, bf, acc3[1][nt], 0, 0, 0);
      }
    }
    #pragma unroll
    for (int nt = 0; nt < 8; nt++) {
      float mx = -__builtin_inff(), mn = __builtin_inff();
      #pragma unroll
      for (int mt = 0; mt < 2; mt++)
        #pragma unroll
        for (int rr = 0; rr < 4; rr++) {
          float y = acc3[mt][nt][rr] + b3l[nt];
          sacc[nt] += y;
          qacc[nt] = fmaf(y, y, qacc[nt]);
          mx = fmaxf(mx, y);
          mn = fminf(mn, y);
        }
      mx = fmaxf(mx, __shfl_xor(mx, 16)); mx = fmaxf(mx, __shfl_xor(mx, 32));
      mn = fminf(mn, __shfl_xor(mn, 16)); mn = fminf(mn, __shfl_xor(mn, 32));
      if (lane < 16) {
        y3max[(size_t)cid * C3_ + nt * 16 + lane] = mx;
        y3min[(size_t)cid * C3_ + nt * 16 + lane] = mn;
      }
    }
  }
  #pragma unroll
  for (int nt = 0; nt < 8; nt++) {
    float s = sacc[nt]; s += __shfl_xor(s, 16); s += __shfl_xor(s, 32);
    float qq = qacc[nt]; qq += __shfl_xor(qq, 16); qq += __shfl_xor(qq, 32);
    if (lane < 16) { atomicAdd(&sld[nt * 16 + lane], s); atomicAdd(&sld[128 + nt * 16 + lane], qq); }
  }
  __syncthreads();
  if (t < 128) { atomicAdd(&stats[256 + t], sld[t]); atomicAdd(&stats[384 + t], sld[128 + t]); }
}

// ---------------- final output ----------------
__global__ __launch_bounds__(256) void k_out(const float* __restrict__ y3max,
                                             const float* __restrict__ y3min,
                                             const float* __restrict__ stats,
                                             const float* __restrict__ g3,
                                             const float* __restrict__ be3,
                                             float* __restrict__ outp) {
  __shared__ float sc[128], sh[128];
  const int t = threadIdx.x;
  if (t < 128) {
    float mean = stats[256 + t] * (1.0f / NTOT_f);
    float var = stats[384 + t] * (1.0f / NTOT_f) - mean * mean;
    float rs = rsqrtf(var + BN_EPS_);
    float s = g3[t] * rs;
    sc[t] = s;
    sh[t] = be3[t] - mean * s;
  }
  __syncthreads();
  int gid = blockIdx.x * 256 + t;
  int m = gid & (M_ - 1);
  int o = (gid >> 11) & 127;
  int b = gid >> 18;
  float s = sc[o], h = sh[o];
  size_t src = ((size_t)(b * M_ + m)) * C3_ + o;
  float v = (s >= 0.0f) ? y3max[src] : y3min[src];
  outp[gid] = fmaxf(fmaf(v, s, h), 0.0f);
}

extern "C" void kernel_launch(void* const* d_in, const int* in_sizes, int n_in,
                              void* d_out, int out_size, void* d_ws, size_t ws_size,
                              hipStream_t stream) {
  const float* xyz  = (const float*)d_in[0];
  const float* feats = (const float*)d_in[1];
  const float* W1 = (const float*)d_in[2];
  const float* b1 = (const float*)d_in[3];
  const float* g1 = (const float*)d_in[4];
  const float* be1 = (const float*)d_in[5];
  const float* W2 = (const float*)d_in[6];
  const float* b2 = (const float*)d_in[7];
  const float* g2 = (const float*)d_in[8];
  const float* be2 = (const float*)d_in[9];
  const float* W3 = (const float*)d_in[10];
  const float* b3 = (const float*)d_in[11];
  const float* g3 = (const float*)d_in[12];
  const float* be3 = (const float*)d_in[13];

  float* out = (float*)d_out;
  float* centers = out;                  // B*M*3
  float* outp = out + (size_t)B_ * M_ * 3;

  float* wsf = (float*)d_ws;
  int* idx = (int*)wsf;
  float* ftT = wsf + WS_FT;
  float* y3max = wsf + WS_Y3MAX;
  float* y3min = wsf + WS_Y3MIN;
  float* stats = wsf + WS_STATS;
  unsigned short* y2b = (unsigned short*)(wsf + WS_Y2F);
  const size_t need = (size_t)WS_Y2F * 4 + (size_t)BM_ * K_ * CIN_ * 2;
  const bool useY2 = ws_size >= need;

  hipMemsetAsync(stats, 0, 512 * sizeof(float), stream);
  k_transpose<<<1024, 256, 0, stream>>>(feats, ftT);
  k_knn<<<1024, 256, 0, stream>>>(xyz, centers, idx);
  k_mf1<<<512, 256, 0, stream>>>(xyz, ftT, idx, W1, b1, stats);
  k_mf2<<<512, 256, 0, stream>>>(xyz, ftT, idx, W1, b1, g1, be1, W2, b2, stats,
                                 useY2 ? y2b : (unsigned short*)nullptr);
  if (useY2) {
    k_mf3f<<<512, 256, 0, stream>>>(y2b, g2, be2, W3, b3, stats, y3max, y3min);
  } else {
    k_mf3<<<512, 256, 0, stream>>>(xyz, ftT, idx, W1, b1, g1, be1, W2, b2, g2, be2,
                                   W3, b3, stats, y3max, y3min);
  }
  k_out<<<8192, 256, 0, stream>>>(y3max, y3min, stats, g3, be3, outp);
}